// Round 7
// baseline (287.259 us; speedup 1.0000x reference)
//
#include <hip/hip_runtime.h>

#define NB 32
#define NC 256
#define NL 128   // NH+NW
#define NCM 128
#define NCO 256
#define NPLANES (NB * NC)   // 8192
#define SUBS 32             // blocks per batch

typedef float v4f __attribute__((ext_vector_type(4)));

// Coherent (agent-scope, sc0/sc1) scalar access for cross-XCD-visible
// intermediates — bypasses the non-coherent per-XCD L2. Only ~8 MB of
// traffic total goes through these; x/out use normal cached paths.
__device__ __forceinline__ void st_coh(float* p, float v) {
    __hip_atomic_store(p, v, __ATOMIC_RELAXED, __HIP_MEMORY_SCOPE_AGENT);
}
__device__ __forceinline__ float ld_coh(const float* p) {
    return __hip_atomic_load(p, __ATOMIC_RELAXED, __HIP_MEMORY_SCOPE_AGENT);
}

// Batch-local barrier across SUBS blocks. Data written via st_coh is at the
// coherent point once retired (syncthreads implies vmcnt(0) drain), so no
// cache maintenance is needed — just an agent-scope counter.
__device__ __forceinline__ void batch_barrier(unsigned* cnt) {
    __syncthreads();
    if (threadIdx.x == 0) {
        __hip_atomic_fetch_add(cnt, 1u, __ATOMIC_RELEASE,
                               __HIP_MEMORY_SCOPE_AGENT);
        while (__hip_atomic_load(cnt, __ATOMIC_RELAXED,
                                 __HIP_MEMORY_SCOPE_AGENT) < (unsigned)SUBS)
            __builtin_amdgcn_s_sleep(2);
    }
    __syncthreads();
}

__global__ __launch_bounds__(256, 4) void k_ca(
    const float* __restrict__ x,
    const float* __restrict__ w1, const float* __restrict__ b1,
    const float* __restrict__ gam, const float* __restrict__ bet,
    const float* __restrict__ mu, const float* __restrict__ var,
    const float* __restrict__ w2, const float* __restrict__ b2,
    const float* __restrict__ w3, const float* __restrict__ b3,
    float* __restrict__ pool, float* __restrict__ a,
    float* __restrict__ gh, float* __restrict__ gw,
    unsigned* __restrict__ bar,
    float* __restrict__ out)
{
    const int blk = blockIdx.x;
    const int b   = blk >> 5;        // batch
    const int sub = blk & 31;        // 0..31 within batch
    const int t   = threadIdx.x;
    __shared__ float smem[4608];     // 18.4 KB (max over phases)

    // ---------------- Phase 1: pooling (8 planes per sub) ----------------
    for (int p = 0; p < 8; ++p) {
        int plane = b * NC + sub * 8 + p;
        const float4* px = (const float4*)(x + (size_t)plane * 4096);
        float4 csum = make_float4(0.f, 0.f, 0.f, 0.f);
        #pragma unroll
        for (int i = 0; i < 4; ++i) {
            int f = t + i * 256;
            float4 v = px[f];
            csum.x += v.x; csum.y += v.y; csum.z += v.z; csum.w += v.w;
            float s = v.x + v.y + v.z + v.w;
            s += __shfl_xor(s, 1);
            s += __shfl_xor(s, 2);
            s += __shfl_xor(s, 4);
            s += __shfl_xor(s, 8);
            if ((t & 15) == 0)
                st_coh(&pool[(size_t)plane * NL + (t >> 4) + 16 * i],
                       s * 0.015625f);                       // xh
        }
        ((float4*)smem)[t] = csum;
        __syncthreads();
        if (t < 64) {
            float acc = 0.f;
            #pragma unroll
            for (int g = 0; g < 16; ++g)
                acc += smem[((t >> 2) + 16 * g) * 4 + (t & 3)];
            st_coh(&pool[(size_t)plane * NL + 64 + t], acc * 0.015625f); // xw
        }
        __syncthreads();
    }
    batch_barrier(&bar[b * 3 + 0]);

    // ---------------- Phase 2: mlp1 (subs 0..7, 16 m each) ----------------
    if (sub < 8) {
        int m0 = sub * 16;
        float* w1t = smem;            // [32][16]  c-major
        float* pt  = smem + 512;      // [32][128] c-major
        const float* poolb = pool + (size_t)b * NC * NL;
        int tm = t & 7, tl = t >> 3;
        float acc[2][4] = {};
        for (int cc = 0; cc < NC; cc += 32) {
            {
                int mi = t & 15, c0 = (t >> 4) * 2;
                float2 wv = *(const float2*)(w1 + (size_t)(m0 + mi) * NC + cc + c0);
                w1t[(c0 + 0) * 16 + mi] = wv.x;
                w1t[(c0 + 1) * 16 + mi] = wv.y;
            }
            #pragma unroll
            for (int k = 0; k < 16; ++k) {     // 32x128 coherent scalar loads
                int idx = t + k * 256;
                int ci = idx >> 7, l = idx & 127;
                pt[ci * 128 + l] = ld_coh(poolb + (size_t)(cc + ci) * NL + l);
            }
            __syncthreads();
            #pragma unroll
            for (int cj = 0; cj < 32; ++cj) {
                float2 wv = *(const float2*)&w1t[cj * 16 + tm * 2];
                float4 pv = *(const float4*)&pt[cj * 128 + tl * 4];
                float pa[4] = {pv.x, pv.y, pv.z, pv.w};
                #pragma unroll
                for (int j = 0; j < 4; ++j) {
                    acc[0][j] += wv.x * pa[j];
                    acc[1][j] += wv.y * pa[j];
                }
            }
            __syncthreads();
        }
        #pragma unroll
        for (int i = 0; i < 2; ++i) {
            int m = m0 + tm * 2 + i;
            float scale = gam[m] * rsqrtf(var[m] + 1e-5f);
            float base = b1[m] - mu[m];
            float bb = bet[m];
            #pragma unroll
            for (int j = 0; j < 4; ++j) {
                float y = (acc[i][j] + base) * scale + bb;
                float hs = y * fminf(fmaxf(y + 3.f, 0.f), 6.f) * (1.f / 6.f);
                st_coh(&a[(size_t)b * NCM * NL + (size_t)m * NL + tl * 4 + j], hs);
            }
        }
    }
    batch_barrier(&bar[b * 3 + 1]);

    // ---------------- Phase 3: gates (subs 0..15) ----------------
    if (sub < 16) {
        int side = sub >> 3, ot = sub & 7;
        const float* wsel = side ? w3 : w2;
        const float* bsel = side ? b3 : b2;
        float* gsel = side ? gw : gh;
        float* wt = smem;             // [32][32] k-major
        float* at = smem + 1024;      // [32][64] k-major
        int to = t & 15, th = t >> 4;
        float acc[2][4] = {};
        const float* ab = a + (size_t)b * NCM * NL + side * 64;
        for (int kc = 0; kc < NCM; kc += 32) {
            {
                int oi = t & 31, k0 = (t >> 5) * 4;
                float4 wv = *(const float4*)(wsel + (size_t)(ot * 32 + oi) * NCM + kc + k0);
                wt[(k0 + 0) * 32 + oi] = wv.x; wt[(k0 + 1) * 32 + oi] = wv.y;
                wt[(k0 + 2) * 32 + oi] = wv.z; wt[(k0 + 3) * 32 + oi] = wv.w;
            }
            #pragma unroll
            for (int k = 0; k < 8; ++k) {      // 32x64 coherent scalar loads
                int idx = t + k * 256;
                int ki = idx >> 6, h = idx & 63;
                at[ki * 64 + h] = ld_coh(ab + (size_t)(kc + ki) * NL + h);
            }
            __syncthreads();
            #pragma unroll
            for (int kj = 0; kj < 32; ++kj) {
                float2 wv = *(const float2*)&wt[kj * 32 + to * 2];
                float4 av = *(const float4*)&at[kj * 64 + th * 4];
                float aa[4] = {av.x, av.y, av.z, av.w};
                #pragma unroll
                for (int j = 0; j < 4; ++j) {
                    acc[0][j] += wv.x * aa[j];
                    acc[1][j] += wv.y * aa[j];
                }
            }
            __syncthreads();
        }
        #pragma unroll
        for (int i = 0; i < 2; ++i) {
            int o = ot * 32 + to * 2 + i;
            float bias = bsel[o];
            #pragma unroll
            for (int j = 0; j < 4; ++j) {
                float v = acc[i][j] + bias;
                float g = 1.f / (1.f + __expf(-v));
                st_coh(&gsel[((size_t)b * NCO + o) * 64 + th * 4 + j], g);
            }
        }
    }
    batch_barrier(&bar[b * 3 + 2]);

    // ---------------- Phase 4: apply (8 planes per sub) ----------------
    {
        // Preload gates for this sub's 8 planes into LDS: gsm[p][0..63]=gh,
        // gsm[p][64..127]=gw  (1024 coherent loads, 4 per thread).
        float* gsm = smem;
        int c0 = sub * 8;
        #pragma unroll
        for (int k = 0; k < 4; ++k) {
            int idx = t + k * 256;
            int p = idx >> 7, r = idx & 127;
            size_t plane = (size_t)b * NC + c0 + p;
            float v = (r < 64) ? ld_coh(&gh[plane * 64 + r])
                               : ld_coh(&gw[plane * 64 + (r - 64)]);
            gsm[p * 128 + r] = v;
        }
        __syncthreads();
        for (int p = 0; p < 8; ++p) {
            size_t plane = (size_t)b * NC + c0 + p;
            const float4* px = (const float4*)(x + plane * 4096);
            float4* po = (float4*)(out + plane * 4096);
            const float* ghp = &gsm[p * 128];
            const float4* gwp = (const float4*)&gsm[p * 128 + 64];
            #pragma unroll
            for (int i = 0; i < 4; ++i) {
                int f = t + i * 256;
                int row = f >> 4, w4 = f & 15;
                float4 v = px[f];
                float g = ghp[row];
                float4 gv = gwp[w4];
                v.x *= g * gv.x; v.y *= g * gv.y;
                v.z *= g * gv.z; v.w *= g * gv.w;
                po[f] = v;
            }
        }
    }
}

extern "C" void kernel_launch(void* const* d_in, const int* in_sizes, int n_in,
                              void* d_out, int out_size, void* d_ws, size_t ws_size,
                              hipStream_t stream) {
    const float* x   = (const float*)d_in[0];
    const float* w1  = (const float*)d_in[1];
    const float* b1  = (const float*)d_in[2];
    const float* gam = (const float*)d_in[3];
    const float* bet = (const float*)d_in[4];
    const float* mu  = (const float*)d_in[5];
    const float* var = (const float*)d_in[6];
    const float* w2  = (const float*)d_in[7];
    const float* b2  = (const float*)d_in[8];
    const float* w3  = (const float*)d_in[9];
    const float* b3  = (const float*)d_in[10];
    float* ws   = (float*)d_ws;
    float* pool = ws;                       // 32*256*128 = 1,048,576 f
    float* a    = ws + 1048576;             // 32*128*128 =   524,288 f
    float* gh   = ws + 1572864;             // 32*256*64  =   524,288 f
    float* gw   = ws + 2097152;             // 32*256*64  =   524,288 f
    unsigned* bar = (unsigned*)(ws + 2621440);   // 32*3 counters
    float* out  = (float*)d_out;

    hipMemsetAsync(bar, 0, NB * 3 * sizeof(unsigned), stream);
    k_ca<<<NB * SUBS, 256, 0, stream>>>(x, w1, b1, gam, bet, mu, var,
                                        w2, b2, w3, b3,
                                        pool, a, gh, gw, bar, out);
}

// Round 8
// 222.183 us; speedup vs baseline: 1.2929x; 1.2929x over previous
//
#include <hip/hip_runtime.h>

#define NB 32
#define NC 256
#define NL 128   // NH+NW
#define NCM 128
#define NCO 256
#define NPLANES (NB * NC)   // 8192
#define SUBS 32             // blocks per batch

typedef float v4f __attribute__((ext_vector_type(4)));

// Coherent (agent-scope, sc0/sc1) scalar access for cross-XCD-visible
// intermediates — bypasses the non-coherent per-XCD L2; completes at the
// Infinity Cache (the agent coherent point) when vmcnt retires.
__device__ __forceinline__ void st_coh(float* p, float v) {
    __hip_atomic_store(p, v, __ATOMIC_RELAXED, __HIP_MEMORY_SCOPE_AGENT);
}
__device__ __forceinline__ float ld_coh(const float* p) {
    return __hip_atomic_load(p, __ATOMIC_RELAXED, __HIP_MEMORY_SCOPE_AGENT);
}

// Batch-local barrier across SUBS blocks. RELAXED fetch_add on purpose:
// an AGENT-scope RELEASE would emit buffer_wbl2 (full L2 writeback) per
// block per barrier — measured ~80us x 3 in round 7. Ordering is already
// guaranteed without it: __syncthreads() drains vmcnt(0) in every wave,
// and all cross-block data uses sc0/sc1 stores that are at the coherent
// point (IC) once vmcnt retires. Consumers read with sc0/sc1 loads.
__device__ __forceinline__ void batch_barrier(unsigned* cnt) {
    __syncthreads();
    if (threadIdx.x == 0) {
        __hip_atomic_fetch_add(cnt, 1u, __ATOMIC_RELAXED,
                               __HIP_MEMORY_SCOPE_AGENT);
        while (__hip_atomic_load(cnt, __ATOMIC_RELAXED,
                                 __HIP_MEMORY_SCOPE_AGENT) < (unsigned)SUBS)
            __builtin_amdgcn_s_sleep(2);
    }
    __syncthreads();
}

__global__ __launch_bounds__(256, 4) void k_ca(
    const float* __restrict__ x,
    const float* __restrict__ w1, const float* __restrict__ b1,
    const float* __restrict__ gam, const float* __restrict__ bet,
    const float* __restrict__ mu, const float* __restrict__ var,
    const float* __restrict__ w2, const float* __restrict__ b2,
    const float* __restrict__ w3, const float* __restrict__ b3,
    float* __restrict__ pool, float* __restrict__ a,
    float* __restrict__ gh, float* __restrict__ gw,
    unsigned* __restrict__ bar,
    float* __restrict__ out)
{
    const int blk = blockIdx.x;
    const int b   = blk >> 5;        // batch
    const int sub = blk & 31;        // 0..31 within batch
    const int t   = threadIdx.x;
    __shared__ float smem[4608];     // 18.4 KB (max over phases)

    // ---------------- Phase 1: pooling (8 planes per sub) ----------------
    for (int p = 0; p < 8; ++p) {
        int plane = b * NC + sub * 8 + p;
        const float4* px = (const float4*)(x + (size_t)plane * 4096);
        float4 csum = make_float4(0.f, 0.f, 0.f, 0.f);
        #pragma unroll
        for (int i = 0; i < 4; ++i) {
            int f = t + i * 256;
            float4 v = px[f];
            csum.x += v.x; csum.y += v.y; csum.z += v.z; csum.w += v.w;
            float s = v.x + v.y + v.z + v.w;
            s += __shfl_xor(s, 1);
            s += __shfl_xor(s, 2);
            s += __shfl_xor(s, 4);
            s += __shfl_xor(s, 8);
            if ((t & 15) == 0)
                st_coh(&pool[(size_t)plane * NL + (t >> 4) + 16 * i],
                       s * 0.015625f);                       // xh
        }
        ((float4*)smem)[t] = csum;
        __syncthreads();
        if (t < 64) {
            float acc = 0.f;
            #pragma unroll
            for (int g = 0; g < 16; ++g)
                acc += smem[((t >> 2) + 16 * g) * 4 + (t & 3)];
            st_coh(&pool[(size_t)plane * NL + 64 + t], acc * 0.015625f); // xw
        }
        __syncthreads();
    }
    batch_barrier(&bar[b * 3 + 0]);

    // ---------------- Phase 2: mlp1 (subs 0..7, 16 m each) ----------------
    if (sub < 8) {
        int m0 = sub * 16;
        float* w1t = smem;            // [32][16]  c-major
        float* pt  = smem + 512;      // [32][128] c-major
        const float* poolb = pool + (size_t)b * NC * NL;
        int tm = t & 7, tl = t >> 3;
        float acc[2][4] = {};
        for (int cc = 0; cc < NC; cc += 32) {
            {
                int mi = t & 15, c0 = (t >> 4) * 2;
                float2 wv = *(const float2*)(w1 + (size_t)(m0 + mi) * NC + cc + c0);
                w1t[(c0 + 0) * 16 + mi] = wv.x;
                w1t[(c0 + 1) * 16 + mi] = wv.y;
            }
            #pragma unroll
            for (int k = 0; k < 16; ++k) {     // 32x128 coherent scalar loads
                int idx = t + k * 256;
                int ci = idx >> 7, l = idx & 127;
                pt[ci * 128 + l] = ld_coh(poolb + (size_t)(cc + ci) * NL + l);
            }
            __syncthreads();
            #pragma unroll
            for (int cj = 0; cj < 32; ++cj) {
                float2 wv = *(const float2*)&w1t[cj * 16 + tm * 2];
                float4 pv = *(const float4*)&pt[cj * 128 + tl * 4];
                float pa[4] = {pv.x, pv.y, pv.z, pv.w};
                #pragma unroll
                for (int j = 0; j < 4; ++j) {
                    acc[0][j] += wv.x * pa[j];
                    acc[1][j] += wv.y * pa[j];
                }
            }
            __syncthreads();
        }
        #pragma unroll
        for (int i = 0; i < 2; ++i) {
            int m = m0 + tm * 2 + i;
            float scale = gam[m] * rsqrtf(var[m] + 1e-5f);
            float base = b1[m] - mu[m];
            float bb = bet[m];
            #pragma unroll
            for (int j = 0; j < 4; ++j) {
                float y = (acc[i][j] + base) * scale + bb;
                float hs = y * fminf(fmaxf(y + 3.f, 0.f), 6.f) * (1.f / 6.f);
                st_coh(&a[(size_t)b * NCM * NL + (size_t)m * NL + tl * 4 + j], hs);
            }
        }
    }
    batch_barrier(&bar[b * 3 + 1]);

    // ---------------- Phase 3: gates (subs 0..15) ----------------
    if (sub < 16) {
        int side = sub >> 3, ot = sub & 7;
        const float* wsel = side ? w3 : w2;
        const float* bsel = side ? b3 : b2;
        float* gsel = side ? gw : gh;
        float* wt = smem;             // [32][32] k-major
        float* at = smem + 1024;      // [32][64] k-major
        int to = t & 15, th = t >> 4;
        float acc[2][4] = {};
        const float* ab = a + (size_t)b * NCM * NL + side * 64;
        for (int kc = 0; kc < NCM; kc += 32) {
            {
                int oi = t & 31, k0 = (t >> 5) * 4;
                float4 wv = *(const float4*)(wsel + (size_t)(ot * 32 + oi) * NCM + kc + k0);
                wt[(k0 + 0) * 32 + oi] = wv.x; wt[(k0 + 1) * 32 + oi] = wv.y;
                wt[(k0 + 2) * 32 + oi] = wv.z; wt[(k0 + 3) * 32 + oi] = wv.w;
            }
            #pragma unroll
            for (int k = 0; k < 8; ++k) {      // 32x64 coherent scalar loads
                int idx = t + k * 256;
                int ki = idx >> 6, h = idx & 63;
                at[ki * 64 + h] = ld_coh(ab + (size_t)(kc + ki) * NL + h);
            }
            __syncthreads();
            #pragma unroll
            for (int kj = 0; kj < 32; ++kj) {
                float2 wv = *(const float2*)&wt[kj * 32 + to * 2];
                float4 av = *(const float4*)&at[kj * 64 + th * 4];
                float aa[4] = {av.x, av.y, av.z, av.w};
                #pragma unroll
                for (int j = 0; j < 4; ++j) {
                    acc[0][j] += wv.x * aa[j];
                    acc[1][j] += wv.y * aa[j];
                }
            }
            __syncthreads();
        }
        #pragma unroll
        for (int i = 0; i < 2; ++i) {
            int o = ot * 32 + to * 2 + i;
            float bias = bsel[o];
            #pragma unroll
            for (int j = 0; j < 4; ++j) {
                float v = acc[i][j] + bias;
                float g = 1.f / (1.f + __expf(-v));
                st_coh(&gsel[((size_t)b * NCO + o) * 64 + th * 4 + j], g);
            }
        }
    }
    batch_barrier(&bar[b * 3 + 2]);

    // ---------------- Phase 4: apply (8 planes per sub) ----------------
    {
        // Preload gates for this sub's 8 planes into LDS: gsm[p][0..63]=gh,
        // gsm[p][64..127]=gw  (1024 coherent loads, 4 per thread).
        float* gsm = smem;
        int c0 = sub * 8;
        #pragma unroll
        for (int k = 0; k < 4; ++k) {
            int idx = t + k * 256;
            int p = idx >> 7, r = idx & 127;
            size_t plane = (size_t)b * NC + c0 + p;
            float v = (r < 64) ? ld_coh(&gh[plane * 64 + r])
                               : ld_coh(&gw[plane * 64 + (r - 64)]);
            gsm[p * 128 + r] = v;
        }
        __syncthreads();
        for (int p = 0; p < 8; ++p) {
            size_t plane = (size_t)b * NC + c0 + p;
            const float4* px = (const float4*)(x + plane * 4096);
            float4* po = (float4*)(out + plane * 4096);
            const float* ghp = &gsm[p * 128];
            const float4* gwp = (const float4*)&gsm[p * 128 + 64];
            #pragma unroll
            for (int i = 0; i < 4; ++i) {
                int f = t + i * 256;
                int row = f >> 4, w4 = f & 15;
                float4 v = px[f];
                float g = ghp[row];
                float4 gv = gwp[w4];
                v.x *= g * gv.x; v.y *= g * gv.y;
                v.z *= g * gv.z; v.w *= g * gv.w;
                po[f] = v;
            }
        }
    }
}

extern "C" void kernel_launch(void* const* d_in, const int* in_sizes, int n_in,
                              void* d_out, int out_size, void* d_ws, size_t ws_size,
                              hipStream_t stream) {
    const float* x   = (const float*)d_in[0];
    const float* w1  = (const float*)d_in[1];
    const float* b1  = (const float*)d_in[2];
    const float* gam = (const float*)d_in[3];
    const float* bet = (const float*)d_in[4];
    const float* mu  = (const float*)d_in[5];
    const float* var = (const float*)d_in[6];
    const float* w2  = (const float*)d_in[7];
    const float* b2  = (const float*)d_in[8];
    const float* w3  = (const float*)d_in[9];
    const float* b3  = (const float*)d_in[10];
    float* ws   = (float*)d_ws;
    float* pool = ws;                       // 32*256*128 = 1,048,576 f
    float* a    = ws + 1048576;             // 32*128*128 =   524,288 f
    float* gh   = ws + 1572864;             // 32*256*64  =   524,288 f
    float* gw   = ws + 2097152;             // 32*256*64  =   524,288 f
    unsigned* bar = (unsigned*)(ws + 2621440);   // 32*3 counters
    float* out  = (float*)d_out;

    hipMemsetAsync(bar, 0, NB * 3 * sizeof(unsigned), stream);
    k_ca<<<NB * SUBS, 256, 0, stream>>>(x, w1, b1, gam, bet, mu, var,
                                        w2, b2, w3, b3,
                                        pool, a, gh, gw, bar, out);
}

// Round 9
// 131.875 us; speedup vs baseline: 2.1783x; 1.6848x over previous
//
#include <hip/hip_runtime.h>

#define NB 32
#define NC 256
#define NL 128   // NH+NW
#define NCM 128
#define NCO 256
#define NPLANES (NB * NC)   // 8192

typedef float v4f __attribute__((ext_vector_type(4)));

// ---------------- Kernel 1: H/W mean pooling ----------------
// grid: 2048 blocks x 256 thr; one plane per WAVE (4 planes/block).
// Zero __syncthreads(). pool layout: [b][c][l], l<64 = xh (mean over W),
// l>=64 = xw (mean over H).
__global__ __launch_bounds__(256) void k_pool(const float* __restrict__ x,
                                              float* __restrict__ pool) {
    int wid  = threadIdx.x >> 6;
    int lane = threadIdx.x & 63;
    int plane = blockIdx.x * 4 + wid;            // b*NC + c
    const float4* px = (const float4*)(x + (size_t)plane * 4096);
    float* pp = pool + (size_t)plane * NL;

    float4 csum = make_float4(0.f, 0.f, 0.f, 0.f);
    #pragma unroll
    for (int i = 0; i < 16; ++i) {
        int f = lane + i * 64;                   // float4 idx; row=f>>4, col4=f&15
        float4 v = px[f];
        csum.x += v.x; csum.y += v.y; csum.z += v.z; csum.w += v.w;
        float s = v.x + v.y + v.z + v.w;
        s += __shfl_xor(s, 1);
        s += __shfl_xor(s, 2);
        s += __shfl_xor(s, 4);
        s += __shfl_xor(s, 8);                   // 16-lane group = one row
        if ((lane & 15) == 0)
            pp[(lane >> 4) + 4 * i] = s * 0.015625f;          // xh
    }
    // csum: cols (lane&15)*4..+3 over rows {lane>>4 + 4i}; combine 4 groups
    csum.x += __shfl_xor(csum.x, 16); csum.y += __shfl_xor(csum.y, 16);
    csum.z += __shfl_xor(csum.z, 16); csum.w += __shfl_xor(csum.w, 16);
    csum.x += __shfl_xor(csum.x, 32); csum.y += __shfl_xor(csum.y, 32);
    csum.z += __shfl_xor(csum.z, 32); csum.w += __shfl_xor(csum.w, 32);
    if (lane < 16) {
        float4 r = make_float4(csum.x * 0.015625f, csum.y * 0.015625f,
                               csum.z * 0.015625f, csum.w * 0.015625f);
        *(float4*)&pp[64 + lane * 4] = r;                     // xw
    }
}

// ---------------- Kernel 2: fused mlp1+BN+hswish+gate+sigmoid ----------------
// grid: (32 b, 2 side), 256 threads. Side chains are independent:
//   side 0: xh -> ah -> gh   side 1: xw -> aw -> gw
// a lives only in LDS; w1/w2/w3 stream from global (L1 line reuse).
__global__ __launch_bounds__(256) void k_mid(const float* __restrict__ pool,
                                             const float* __restrict__ w1,
                                             const float* __restrict__ b1,
                                             const float* __restrict__ gam,
                                             const float* __restrict__ bet,
                                             const float* __restrict__ mu,
                                             const float* __restrict__ var,
                                             const float* __restrict__ w2,
                                             const float* __restrict__ b2,
                                             const float* __restrict__ w3,
                                             const float* __restrict__ b3,
                                             float* __restrict__ gh,
                                             float* __restrict__ gw) {
    const int b = blockIdx.x, side = blockIdx.y;
    const int t = threadIdx.x;
    const float* wsel = side ? w3 : w2;
    const float* bsel = side ? b3 : b2;
    float* gsel = side ? gw : gh;
    const float* poolb = pool + (size_t)b * NC * NL + side * 64;

    __shared__ float sm[8704];     // A: pt[64][68] (4352) ; B: a_sm[128][68]
    float* pt   = sm;
    float* a_sm = sm;

    // ---- Step A: y[m][l] = sum_c w1[m][c]*poolb[c][l]; thread: 4m x 8l ----
    int tm = t & 31, tl = t >> 5;               // m=tm*4+i, l=tl*8+j
    float acc[4][8] = {};
    for (int cc = 0; cc < NC; cc += 64) {
        #pragma unroll
        for (int k = 0; k < 4; ++k) {           // stage pool chunk 64c x 64l
            int fidx = t + k * 256;
            int ci = fidx >> 4, l4 = fidx & 15;
            float4 v = *(const float4*)(poolb + (size_t)(cc + ci) * NL + l4 * 4);
            *(float4*)&pt[ci * 68 + l4 * 4] = v;
        }
        __syncthreads();
        #pragma unroll 4
        for (int cj4 = 0; cj4 < 16; ++cj4) {
            v4f wv[4];
            #pragma unroll
            for (int i = 0; i < 4; ++i)
                wv[i] = *(const v4f*)(w1 + (size_t)(tm * 4 + i) * NC + cc + cj4 * 4);
            #pragma unroll
            for (int cjj = 0; cjj < 4; ++cjj) {
                int cj = cj4 * 4 + cjj;
                float4 p0 = *(const float4*)&pt[cj * 68 + tl * 8];
                float4 p1 = *(const float4*)&pt[cj * 68 + tl * 8 + 4];
                float pa[8] = {p0.x, p0.y, p0.z, p0.w, p1.x, p1.y, p1.z, p1.w};
                #pragma unroll
                for (int i = 0; i < 4; ++i) {
                    float w = wv[i][cjj];
                    #pragma unroll
                    for (int j = 0; j < 8; ++j)
                        acc[i][j] += w * pa[j];
                }
            }
        }
        __syncthreads();
    }
    // BN + hswish -> a_sm[m][l]
    #pragma unroll
    for (int i = 0; i < 4; ++i) {
        int m = tm * 4 + i;
        float scale = gam[m] * rsqrtf(var[m] + 1e-5f);
        float base  = b1[m] - mu[m];
        float bb    = bet[m];
        float r[8];
        #pragma unroll
        for (int j = 0; j < 8; ++j) {
            float y = (acc[i][j] + base) * scale + bb;
            r[j] = y * fminf(fmaxf(y + 3.f, 0.f), 6.f) * (1.f / 6.f);
        }
        *(float4*)&a_sm[m * 68 + tl * 8]     = make_float4(r[0], r[1], r[2], r[3]);
        *(float4*)&a_sm[m * 68 + tl * 8 + 4] = make_float4(r[4], r[5], r[6], r[7]);
    }
    __syncthreads();

    // ---- Step B: g[o][l] = sigmoid(sum_m wsel[o][m]*a_sm[m][l] + bsel[o]) ----
    int to = t & 31, tlb = t >> 5;              // o=to*8+i, l=tlb*8+j
    float acc2[8][8] = {};
    #pragma unroll 2
    for (int mj4 = 0; mj4 < 32; ++mj4) {
        v4f wv[8];
        #pragma unroll
        for (int i = 0; i < 8; ++i)
            wv[i] = *(const v4f*)(wsel + (size_t)(to * 8 + i) * NCM + mj4 * 4);
        #pragma unroll
        for (int mjj = 0; mjj < 4; ++mjj) {
            int mj = mj4 * 4 + mjj;
            float4 a0 = *(const float4*)&a_sm[mj * 68 + tlb * 8];
            float4 a1 = *(const float4*)&a_sm[mj * 68 + tlb * 8 + 4];
            float aa[8] = {a0.x, a0.y, a0.z, a0.w, a1.x, a1.y, a1.z, a1.w};
            #pragma unroll
            for (int i = 0; i < 8; ++i) {
                float w = wv[i][mjj];
                #pragma unroll
                for (int j = 0; j < 8; ++j)
                    acc2[i][j] += w * aa[j];
            }
        }
    }
    #pragma unroll
    for (int i = 0; i < 8; ++i) {
        int o = to * 8 + i;
        float bias = bsel[o];
        float g[8];
        #pragma unroll
        for (int j = 0; j < 8; ++j)
            g[j] = 1.f / (1.f + __expf(-(acc2[i][j] + bias)));
        float* gp = gsel + ((size_t)b * NCO + o) * 64 + tlb * 8;
        *(float4*)&gp[0] = make_float4(g[0], g[1], g[2], g[3]);
        *(float4*)&gp[4] = make_float4(g[4], g[5], g[6], g[7]);
    }
}

// ---------------- Kernel 3: out = x * gh[h] * gw[w] ----------------
__global__ __launch_bounds__(256) void k_apply(const float* __restrict__ x,
                                               const float* __restrict__ gh,
                                               const float* __restrict__ gw,
                                               float* __restrict__ out) {
    int t = threadIdx.x;
    #pragma unroll
    for (int p = 0; p < 2; ++p) {
        int plane = blockIdx.x * 2 + p;      // b*NC + c (o == c since Co==C)
        const float4* px = (const float4*)(x + (size_t)plane * 4096);
        float4* po = (float4*)(out + (size_t)plane * 4096);
        const float* ghp = gh + (size_t)plane * 64;
        const float4* gwp = (const float4*)(gw + (size_t)plane * 64);
        #pragma unroll
        for (int i = 0; i < 4; ++i) {
            int f = t + i * 256;
            int row = f >> 4, w4 = f & 15;
            float4 v = px[f];
            float g = ghp[row];
            float4 gv = gwp[w4];
            v.x *= g * gv.x; v.y *= g * gv.y;
            v.z *= g * gv.z; v.w *= g * gv.w;
            po[f] = v;
        }
    }
}

extern "C" void kernel_launch(void* const* d_in, const int* in_sizes, int n_in,
                              void* d_out, int out_size, void* d_ws, size_t ws_size,
                              hipStream_t stream) {
    const float* x   = (const float*)d_in[0];
    const float* w1  = (const float*)d_in[1];
    const float* b1  = (const float*)d_in[2];
    const float* gam = (const float*)d_in[3];
    const float* bet = (const float*)d_in[4];
    const float* mu  = (const float*)d_in[5];
    const float* var = (const float*)d_in[6];
    const float* w2  = (const float*)d_in[7];
    const float* b2  = (const float*)d_in[8];
    const float* w3  = (const float*)d_in[9];
    const float* b3  = (const float*)d_in[10];
    float* ws   = (float*)d_ws;
    float* pool = ws;                       // 32*256*128 = 1,048,576 f
    float* gh   = ws + 1048576;             // 32*256*64  =   524,288 f
    float* gw   = ws + 1572864;             // 32*256*64  =   524,288 f
    float* out  = (float*)d_out;

    k_pool<<<NPLANES / 4, 256, 0, stream>>>(x, pool);
    k_mid<<<dim3(NB, 2), 256, 0, stream>>>(pool, w1, b1, gam, bet, mu, var,
                                           w2, b2, w3, b3, gh, gw);
    k_apply<<<NPLANES / 2, 256, 0, stream>>>(x, gh, gw, out);
}